// Round 3
// baseline (527.455 us; speedup 1.0000x reference)
//
#include <hip/hip_runtime.h>
#include <hip/hip_bf16.h>

// Problem constants (fixed by the reference setup)
#define H_DIM  128
#define NGRAPH 8192
#define NTOTAL 409600
#define CH2    16                   // nodes per k2a block (one 16x16x32 MFMA tile row)

typedef __attribute__((ext_vector_type(8))) short    s16x8;   // 8 bf16
typedef __attribute__((ext_vector_type(4))) float    f32x4;   // MFMA accumulator
typedef __attribute__((ext_vector_type(4))) unsigned u32x4;

__device__ __forceinline__ unsigned short f2bf(float f) {
    unsigned int u = __float_as_uint(f);
    unsigned int r = u + 0x7fffu + ((u >> 16) & 1u);   // RNE
    return (unsigned short)(r >> 16);
}

// ---------------- K0: W2 f32 -> bf16 (row-major [h][k]) ----------------
__global__ void k0_w2(const float* __restrict__ W2w, unsigned short* __restrict__ w2bf) {
    int i = blockIdx.x * 256 + threadIdx.x;   // grid covers exactly 128*128
    w2bf[i] = f2bf(W2w[i]);
}

// ---------------- K1: a_g = v_n @ W1^T + (W1_b + W2_b) -----------------
__global__ __launch_bounds__(128) void k1_ag(
    const float* __restrict__ node_emb,
    const int*   __restrict__ last_idx,
    const float* __restrict__ W1w,
    const float* __restrict__ W1b,
    const float* __restrict__ W2b,
    float* __restrict__ a_g)
{
    __shared__ float vn[4][H_DIM];
    const int tid = threadIdx.x;
    const int g0  = blockIdx.x * 4;
    #pragma unroll
    for (int g = 0; g < 4; g++) {
        int li = last_idx[g0 + g];
        vn[g][tid] = node_emb[(size_t)li * H_DIM + tid];
    }
    __syncthreads();
    float b = W1b[tid] + W2b[tid];
    float a0 = b, a1 = b, a2 = b, a3 = b;
    const float* wrow = W1w + (size_t)tid * H_DIM;
    #pragma unroll 8
    for (int k = 0; k < H_DIM; k += 4) {
        float4 w = *reinterpret_cast<const float4*>(wrow + k);
        a0 += w.x * vn[0][k] + w.y * vn[0][k+1] + w.z * vn[0][k+2] + w.w * vn[0][k+3];
        a1 += w.x * vn[1][k] + w.y * vn[1][k+1] + w.z * vn[1][k+2] + w.w * vn[1][k+3];
        a2 += w.x * vn[2][k] + w.y * vn[2][k+1] + w.z * vn[2][k+2] + w.w * vn[2][k+3];
        a3 += w.x * vn[3][k] + w.y * vn[3][k+1] + w.z * vn[3][k+2] + w.w * vn[3][k+3];
    }
    a_g[(size_t)(g0 + 0) * H_DIM + tid] = a0;
    a_g[(size_t)(g0 + 1) * H_DIM + tid] = a1;
    a_g[(size_t)(g0 + 2) * H_DIM + tid] = a2;
    a_g[(size_t)(g0 + 3) * H_DIM + tid] = a3;
}

// ---------------- K2a: coef[n] = nc * (q . sigmoid(node@W2^T + a_g) + qb)
// One wave per block, 16 nodes. No LDS tiles, no barriers, no atomics.
__global__ __launch_bounds__(64, 3) void k2a_alpha(
    const float* __restrict__ node_emb,
    const float* __restrict__ num_count,
    const int*   __restrict__ seg_ids,
    const float* __restrict__ a_g,
    const unsigned short* __restrict__ w2bf,
    const float* __restrict__ q_w,
    const float* __restrict__ q_b,
    float* __restrict__ coef)
{
    const int lane = threadIdx.x;          // 0..63
    const int l16 = lane & 15, lq = lane >> 4;
    const int nb  = blockIdx.x * CH2;

    // --- early scalar-ish loads ---
    int4   seg4 = *reinterpret_cast<const int4*>(seg_ids + nb + lq * 4);
    float4 nc4  = *reinterpret_cast<const float4*>(num_count + nb + lq * 4);
    const float qb0 = q_b[0];
    float qv[8];
    #pragma unroll
    for (int nt = 0; nt < 8; nt++) qv[nt] = q_w[nt * 16 + l16];
    int sg[4] = {seg4.x, seg4.y, seg4.z, seg4.w};
    float ncv[4] = {nc4.x, nc4.y, nc4.z, nc4.w};

    // --- A fragments: direct global f32 -> bf16 in-register ---
    // lane holds node row (nb+l16), k = lq*8 + ks*32 .. +7
    s16x8 af[4];
    const float* nrow = node_emb + (size_t)(nb + l16) * H_DIM + lq * 8;
    #pragma unroll
    for (int ks = 0; ks < 4; ks++) {
        float4 f0 = *reinterpret_cast<const float4*>(nrow + ks * 32);
        float4 f1 = *reinterpret_cast<const float4*>(nrow + ks * 32 + 4);
        unsigned p0, p1, p2, p3;
        asm("v_cvt_pk_bf16_f32 %0, %1, %2" : "=v"(p0) : "v"(f0.x), "v"(f0.y));
        asm("v_cvt_pk_bf16_f32 %0, %1, %2" : "=v"(p1) : "v"(f0.z), "v"(f0.w));
        asm("v_cvt_pk_bf16_f32 %0, %1, %2" : "=v"(p2) : "v"(f1.x), "v"(f1.y));
        asm("v_cvt_pk_bf16_f32 %0, %1, %2" : "=v"(p3) : "v"(f1.z), "v"(f1.w));
        union { u32x4 u; s16x8 s; } cv;
        cv.u = u32x4{p0, p1, p2, p3};
        af[ks] = cv.s;
    }

    // --- a_g gather (issue before MFMA; consumed after) ---
    float ag[4][8];
    #pragma unroll
    for (int rr = 0; rr < 4; rr++) {
        const float* ar = a_g + (size_t)sg[rr] * H_DIM + l16;
        #pragma unroll
        for (int nt = 0; nt < 8; nt++) ag[rr][nt] = ar[nt * 16];
    }

    // --- MFMA: z[m][h], h covered by nt=0..7 tiles of 16 ---
    f32x4 acc[8];
    #pragma unroll
    for (int nt = 0; nt < 8; nt++) acc[nt] = f32x4{0.f, 0.f, 0.f, 0.f};
    #pragma unroll
    for (int nt = 0; nt < 8; nt++) {
        #pragma unroll
        for (int ks = 0; ks < 4; ks++) {
            // B-frag: W2 row (nt*16+l16), k = lq*8 + ks*32 (bf16, L1/L2-hot)
            s16x8 bf = *reinterpret_cast<const s16x8*>(
                w2bf + (size_t)(nt * 16 + l16) * H_DIM + lq * 8 + ks * 32);
            acc[nt] = __builtin_amdgcn_mfma_f32_16x16x32_bf16(af[ks], bf, acc[nt], 0, 0, 0);
        }
    }

    // --- alpha: per row m = lq*4+rr, sum over h; pure shfl reduce ---
    #pragma unroll
    for (int rr = 0; rr < 4; rr++) {
        float p = 0.f;
        #pragma unroll
        for (int nt = 0; nt < 8; nt++) {
            float z = acc[nt][rr] + ag[rr][nt];
            float e = __expf(-z);
            p += qv[nt] * __builtin_amdgcn_rcpf(1.f + e);
        }
        p += __shfl_xor(p, 1, 64);
        p += __shfl_xor(p, 2, 64);
        p += __shfl_xor(p, 4, 64);
        p += __shfl_xor(p, 8, 64);
        if (l16 == 0)
            coef[nb + lq * 4 + rr] = ncv[rr] * (p + qb0);
    }
}

// ---------------- K2b: s_g[g] = sum_{n in graph g} coef[n] * node[n] ---
// One block per graph; contiguous span; register accumulation; no atomics.
__global__ __launch_bounds__(128) void k2b_segsum(
    const float* __restrict__ node_emb,
    const float* __restrict__ coef,
    const int*   __restrict__ last_idx,
    float* __restrict__ s_g)
{
    const int g = blockIdx.x;
    const int h = threadIdx.x;
    const int start = (g == 0) ? 0 : last_idx[g - 1] + 1;
    const int end   = last_idx[g];

    float a0 = 0.f, a1 = 0.f, a2 = 0.f, a3 = 0.f;
    int n = start;
    for (; n + 3 <= end; n += 4) {
        a0 += coef[n]     * node_emb[(size_t)n       * H_DIM + h];
        a1 += coef[n + 1] * node_emb[(size_t)(n + 1) * H_DIM + h];
        a2 += coef[n + 2] * node_emb[(size_t)(n + 2) * H_DIM + h];
        a3 += coef[n + 3] * node_emb[(size_t)(n + 3) * H_DIM + h];
    }
    for (; n <= end; n++)
        a0 += coef[n] * node_emb[(size_t)n * H_DIM + h];
    s_g[(size_t)g * H_DIM + h] = (a0 + a1) + (a2 + a3);
}

// ---------------- K3: s_h = [v_n | s_g] @ W3^T + W3_b ------------------
__global__ __launch_bounds__(128) void k3_out(
    const float* __restrict__ node_emb,
    const int*   __restrict__ last_idx,
    const float* __restrict__ s_g,
    const float* __restrict__ W3w,
    const float* __restrict__ W3b,
    float* __restrict__ out)
{
    __shared__ float cat[8][2 * H_DIM];
    const int tid = threadIdx.x;
    const int g0  = blockIdx.x * 8;
    #pragma unroll
    for (int g = 0; g < 8; g++) {
        cat[g][tid]         = node_emb[(size_t)last_idx[g0 + g] * H_DIM + tid];
        cat[g][H_DIM + tid] = s_g[(size_t)(g0 + g) * H_DIM + tid];
    }
    __syncthreads();
    float acc[8];
    float b = W3b[tid];
    #pragma unroll
    for (int g = 0; g < 8; g++) acc[g] = b;
    const float* wrow = W3w + (size_t)tid * (2 * H_DIM);
    for (int k = 0; k < 2 * H_DIM; k += 4) {
        float4 w = *reinterpret_cast<const float4*>(wrow + k);
        #pragma unroll
        for (int g = 0; g < 8; g++)
            acc[g] += w.x * cat[g][k] + w.y * cat[g][k+1]
                    + w.z * cat[g][k+2] + w.w * cat[g][k+3];
    }
    #pragma unroll
    for (int g = 0; g < 8; g++)
        out[(size_t)(g0 + g) * H_DIM + tid] = acc[g];
}

extern "C" void kernel_launch(void* const* d_in, const int* in_sizes, int n_in,
                              void* d_out, int out_size, void* d_ws, size_t ws_size,
                              hipStream_t stream) {
    const float* node_emb  = (const float*)d_in[0];
    const float* num_count = (const float*)d_in[1];
    // d_in[2] sections: unused
    const int*   seg_ids   = (const int*)d_in[3];
    const int*   last_idx  = (const int*)d_in[4];
    // d_in[5..8] unused
    const float* W1w = (const float*)d_in[9];
    const float* W1b = (const float*)d_in[10];
    const float* W2w = (const float*)d_in[11];
    const float* W2b = (const float*)d_in[12];
    const float* qw  = (const float*)d_in[13];
    const float* qb  = (const float*)d_in[14];
    const float* W3w = (const float*)d_in[15];
    const float* W3b = (const float*)d_in[16];
    float* out = (float*)d_out;

    char* ws = (char*)d_ws;
    float* a_g  = (float*)(ws);                          // 4 MB
    float* s_g  = (float*)(ws + (4u << 20));             // 4 MB
    float* coef = (float*)(ws + (8u << 20));             // 1.6 MB
    unsigned short* w2bf = (unsigned short*)(ws + (10u << 20));  // 32 KB

    k0_w2     <<<64,          256, 0, stream>>>(W2w, w2bf);
    k1_ag     <<<NGRAPH / 4,  128, 0, stream>>>(node_emb, last_idx, W1w, W1b, W2b, a_g);
    k2a_alpha <<<NTOTAL / CH2, 64, 0, stream>>>(node_emb, num_count, seg_ids, a_g,
                                                w2bf, qw, qb, coef);
    k2b_segsum<<<NGRAPH,      128, 0, stream>>>(node_emb, coef, last_idx, s_g);
    k3_out    <<<NGRAPH / 8,  128, 0, stream>>>(node_emb, last_idx, s_g, W3w, W3b, out);
}

// Round 4
// 113.009 us; speedup vs baseline: 4.6674x; 4.6674x over previous
//
#include <hip/hip_runtime.h>
#include <hip/hip_bf16.h>

// Problem constants (fixed by the reference setup)
#define H_DIM  128
#define NGRAPH 8192
#define NTOTAL 409600

typedef __attribute__((ext_vector_type(8))) short    s16x8;   // 8 bf16
typedef __attribute__((ext_vector_type(4))) float    f32x4;   // MFMA accumulator
typedef __attribute__((ext_vector_type(4))) unsigned u32x4;

__device__ __forceinline__ unsigned short f2bf(float f) {
    unsigned int u = __float_as_uint(f);
    unsigned int r = u + 0x7fffu + ((u >> 16) & 1u);   // RNE
    return (unsigned short)(r >> 16);
}

// ---------------- K0: W2 f32 -> bf16 (row-major [h][k]) ----------------
__global__ void k0_w2(const float* __restrict__ W2w, unsigned short* __restrict__ w2bf) {
    int i = blockIdx.x * 256 + threadIdx.x;   // grid covers exactly 128*128
    w2bf[i] = f2bf(W2w[i]);
}

// ---------------- K1: a_g = v_n @ W1^T + (W1_b + W2_b) -----------------
__global__ __launch_bounds__(128) void k1_ag(
    const float* __restrict__ node_emb,
    const int*   __restrict__ last_idx,
    const float* __restrict__ W1w,
    const float* __restrict__ W1b,
    const float* __restrict__ W2b,
    float* __restrict__ a_g)
{
    __shared__ float vn[4][H_DIM];
    const int tid = threadIdx.x;
    const int g0  = blockIdx.x * 4;
    #pragma unroll
    for (int g = 0; g < 4; g++) {
        int li = last_idx[g0 + g];
        vn[g][tid] = node_emb[(size_t)li * H_DIM + tid];
    }
    __syncthreads();
    float b = W1b[tid] + W2b[tid];
    float a0 = b, a1 = b, a2 = b, a3 = b;
    const float* wrow = W1w + (size_t)tid * H_DIM;
    #pragma unroll 8
    for (int k = 0; k < H_DIM; k += 4) {
        float4 w = *reinterpret_cast<const float4*>(wrow + k);
        a0 += w.x * vn[0][k] + w.y * vn[0][k+1] + w.z * vn[0][k+2] + w.w * vn[0][k+3];
        a1 += w.x * vn[1][k] + w.y * vn[1][k+1] + w.z * vn[1][k+2] + w.w * vn[1][k+3];
        a2 += w.x * vn[2][k] + w.y * vn[2][k+1] + w.z * vn[2][k+2] + w.w * vn[2][k+3];
        a3 += w.x * vn[3][k] + w.y * vn[3][k+1] + w.z * vn[3][k+2] + w.w * vn[3][k+3];
    }
    a_g[(size_t)(g0 + 0) * H_DIM + tid] = a0;
    a_g[(size_t)(g0 + 1) * H_DIM + tid] = a1;
    a_g[(size_t)(g0 + 2) * H_DIM + tid] = a2;
    a_g[(size_t)(g0 + 3) * H_DIM + tid] = a3;
}

// ---------------- K2: fully fused alpha + segment-sum ------------------
// 6400 blocks x 256 threads. One barrier (W2 stage). Each WAVE owns 16
// nodes independently: swapped z-MFMA (z^T), in-lane alpha, identity-MFMA
// transpose for the segmented sum, global atomics per run.
__global__ __launch_bounds__(256, 4) void k2_fused(
    const float* __restrict__ node_emb,
    const float* __restrict__ num_count,
    const int*   __restrict__ seg_ids,
    const float* __restrict__ a_g,
    const unsigned short* __restrict__ w2bf,
    const float* __restrict__ q_w,
    const float* __restrict__ q_b,
    float* __restrict__ s_g)
{
    __shared__ __align__(16) char w2s[H_DIM * 256];   // 32 KB, swizzled

    const int tid = threadIdx.x;
    // --- stage W2 bf16 -> LDS (once per block), XOR swizzled ---
    {
        const uint4* wsrc = reinterpret_cast<const uint4*>(w2bf);
        #pragma unroll
        for (int i = 0; i < 8; i++) {
            int c = i * 256 + tid;
            uint4 v = wsrc[c];
            int byte = c << 4;
            int row  = byte >> 8;
            *reinterpret_cast<uint4*>(w2s + (byte ^ ((row & 7) << 4))) = v;
        }
    }

    const int lane = tid & 63;
    const int wid  = tid >> 6;
    const int l16 = lane & 15, lq = lane >> 4;
    const int nb  = (blockIdx.x * 4 + wid) * 16;      // this wave's 16 nodes

    // --- per-row scalars (row = l16) ---
    const int   sgl = seg_ids[nb + l16];
    const float ncl = num_count[nb + l16];
    const float qb0 = q_b[0];

    // --- q_w and a_g: float4 loads, h = nt*16 + lq*4 + rr ---
    float qv[8][4], ag[8][4];
    #pragma unroll
    for (int nt = 0; nt < 8; nt++) {
        float4 q4 = *reinterpret_cast<const float4*>(q_w + nt * 16 + lq * 4);
        qv[nt][0] = q4.x; qv[nt][1] = q4.y; qv[nt][2] = q4.z; qv[nt][3] = q4.w;
        float4 a4 = *reinterpret_cast<const float4*>(
            a_g + (size_t)sgl * H_DIM + nt * 16 + lq * 4);
        ag[nt][0] = a4.x; ag[nt][1] = a4.y; ag[nt][2] = a4.z; ag[nt][3] = a4.w;
    }

    // --- A/B node fragments: row l16, cols lq*8 + ks*32 .. +7 (bf16) ---
    s16x8 af[4];
    const float* nrow = node_emb + (size_t)(nb + l16) * H_DIM + lq * 8;
    #pragma unroll
    for (int ks = 0; ks < 4; ks++) {
        float4 f0 = *reinterpret_cast<const float4*>(nrow + ks * 32);
        float4 f1 = *reinterpret_cast<const float4*>(nrow + ks * 32 + 4);
        unsigned p0, p1, p2, p3;
        asm("v_cvt_pk_bf16_f32 %0, %1, %2" : "=v"(p0) : "v"(f0.x), "v"(f0.y));
        asm("v_cvt_pk_bf16_f32 %0, %1, %2" : "=v"(p1) : "v"(f0.z), "v"(f0.w));
        asm("v_cvt_pk_bf16_f32 %0, %1, %2" : "=v"(p2) : "v"(f1.x), "v"(f1.y));
        asm("v_cvt_pk_bf16_f32 %0, %1, %2" : "=v"(p3) : "v"(f1.z), "v"(f1.w));
        union { u32x4 u; s16x8 s; } cv;
        cv.u = u32x4{p0, p1, p2, p3};
        af[ks] = cv.s;
    }

    __syncthreads();   // w2s ready (only barrier)

    // --- swapped MFMA: acc[nt] = z^T tile -> lane holds z[l16][h] -------
    // A = W2 frag (rows nt*16+l16), B = node frag (col j = node row l16)
    f32x4 acc[8];
    #pragma unroll
    for (int nt = 0; nt < 8; nt++) acc[nt] = f32x4{0.f, 0.f, 0.f, 0.f};
    #pragma unroll
    for (int ks = 0; ks < 4; ks++) {
        #pragma unroll
        for (int nt = 0; nt < 8; nt++) {
            int row  = nt * 16 + l16;
            int byte = (row << 8) | ((lq * 8 + ks * 32) << 1);
            byte ^= (row & 7) << 4;
            s16x8 wfr = *reinterpret_cast<const s16x8*>(w2s + byte);
            acc[nt] = __builtin_amdgcn_mfma_f32_16x16x32_bf16(wfr, af[ks], acc[nt], 0, 0, 0);
        }
    }

    // --- alpha[l16] = sum_h sigmoid(z + a_g) * q_w[h]; h in-lane + xor16/32
    float p = 0.f;
    #pragma unroll
    for (int nt = 0; nt < 8; nt++) {
        #pragma unroll
        for (int rr = 0; rr < 4; rr++) {
            float z = acc[nt][rr] + ag[nt][rr];
            float e = __expf(-z);
            p += qv[nt][rr] * __builtin_amdgcn_rcpf(1.f + e);
        }
    }
    p += __shfl_xor(p, 16, 64);
    p += __shfl_xor(p, 32, 64);
    const float coefl = ncl * (p + qb0);   // coef for row l16, at every lane

    // --- identity-MFMA transpose: accT[ks][b][rr] = node[lq*4+rr][ks*32+b*16+l16]
    s16x8 ib[2];
    #pragma unroll
    for (int b = 0; b < 2; b++) {
        int kk = l16 + 16 * b;
        #pragma unroll
        for (int e = 0; e < 8; e++)
            ib[b][e] = (kk == lq * 8 + e) ? (short)0x3F80 : (short)0;
    }
    f32x4 accT[4][2];
    #pragma unroll
    for (int ks = 0; ks < 4; ks++)
        #pragma unroll
        for (int b = 0; b < 2; b++)
            accT[ks][b] = __builtin_amdgcn_mfma_f32_16x16x32_bf16(
                              af[ks], ib[b], f32x4{0.f, 0.f, 0.f, 0.f}, 0, 0, 0);

    // --- segmented sum over the wave's 16 rows, run by run ---------------
    int r0 = 0;
    while (r0 < 16) {
        const int cur = __shfl(sgl, r0, 64);                 // wave-uniform
        unsigned long long diff = __ballot(sgl != cur) & 0xFFFFull;
        diff &= ~((1ull << r0) - 1ull);
        const int r1 = diff ? (int)__builtin_ctzll(diff) : 16;

        const float cmask = (sgl == cur) ? coefl : 0.f;      // masked coef of row l16
        float cm[4];
        #pragma unroll
        for (int rr = 0; rr < 4; rr++)
            cm[rr] = __shfl(cmask, lq * 4 + rr, 64);

        #pragma unroll
        for (int ks = 0; ks < 4; ks++) {
            #pragma unroll
            for (int b = 0; b < 2; b++) {
                float s = cm[0] * accT[ks][b][0] + cm[1] * accT[ks][b][1]
                        + cm[2] * accT[ks][b][2] + cm[3] * accT[ks][b][3];
                s += __shfl_xor(s, 16, 64);
                s += __shfl_xor(s, 32, 64);
                if (lq == 0)
                    atomicAdd(s_g + (size_t)cur * H_DIM + ks * 32 + b * 16 + l16, s);
            }
        }
        r0 = r1;
    }
}

// ---------------- K3: s_h = [v_n | s_g] @ W3^T + W3_b ------------------
__global__ __launch_bounds__(128) void k3_out(
    const float* __restrict__ node_emb,
    const int*   __restrict__ last_idx,
    const float* __restrict__ s_g,
    const float* __restrict__ W3w,
    const float* __restrict__ W3b,
    float* __restrict__ out)
{
    __shared__ float cat[8][2 * H_DIM];
    const int tid = threadIdx.x;
    const int g0  = blockIdx.x * 8;
    #pragma unroll
    for (int g = 0; g < 8; g++) {
        cat[g][tid]         = node_emb[(size_t)last_idx[g0 + g] * H_DIM + tid];
        cat[g][H_DIM + tid] = s_g[(size_t)(g0 + g) * H_DIM + tid];
    }
    __syncthreads();
    float acc[8];
    float b = W3b[tid];
    #pragma unroll
    for (int g = 0; g < 8; g++) acc[g] = b;
    const float* wrow = W3w + (size_t)tid * (2 * H_DIM);
    for (int k = 0; k < 2 * H_DIM; k += 4) {
        float4 w = *reinterpret_cast<const float4*>(wrow + k);
        #pragma unroll
        for (int g = 0; g < 8; g++)
            acc[g] += w.x * cat[g][k] + w.y * cat[g][k+1]
                    + w.z * cat[g][k+2] + w.w * cat[g][k+3];
    }
    #pragma unroll
    for (int g = 0; g < 8; g++)
        out[(size_t)(g0 + g) * H_DIM + tid] = acc[g];
}

extern "C" void kernel_launch(void* const* d_in, const int* in_sizes, int n_in,
                              void* d_out, int out_size, void* d_ws, size_t ws_size,
                              hipStream_t stream) {
    const float* node_emb  = (const float*)d_in[0];
    const float* num_count = (const float*)d_in[1];
    // d_in[2] sections: unused
    const int*   seg_ids   = (const int*)d_in[3];
    const int*   last_idx  = (const int*)d_in[4];
    // d_in[5..8] unused
    const float* W1w = (const float*)d_in[9];
    const float* W1b = (const float*)d_in[10];
    const float* W2w = (const float*)d_in[11];
    const float* W2b = (const float*)d_in[12];
    const float* qw  = (const float*)d_in[13];
    const float* qb  = (const float*)d_in[14];
    const float* W3w = (const float*)d_in[15];
    const float* W3b = (const float*)d_in[16];
    float* out = (float*)d_out;

    char* ws = (char*)d_ws;
    float* a_g = (float*)(ws);                          // 4 MB
    float* s_g = (float*)(ws + (4u << 20));             // 4 MB
    unsigned short* w2bf = (unsigned short*)(ws + (8u << 20));   // 32 KB

    hipMemsetAsync(s_g, 0, (size_t)NGRAPH * H_DIM * sizeof(float), stream);
    k0_w2   <<<64,          256, 0, stream>>>(W2w, w2bf);
    k1_ag   <<<NGRAPH / 4,  128, 0, stream>>>(node_emb, last_idx, W1w, W1b, W2b, a_g);
    k2_fused<<<NTOTAL / 64, 256, 0, stream>>>(node_emb, num_count, seg_ids, a_g,
                                              w2bf, qw, qb, s_g);
    k3_out  <<<NGRAPH / 8,  128, 0, stream>>>(node_emb, last_idx, s_g, W3w, W3b, out);
}

// Round 5
// 109.146 us; speedup vs baseline: 4.8326x; 1.0354x over previous
//
#include <hip/hip_runtime.h>
#include <hip/hip_bf16.h>

// Problem constants (fixed by the reference setup)
#define H_DIM  128
#define NGRAPH 8192
#define NTOTAL 409600

typedef __attribute__((ext_vector_type(8))) short    s16x8;   // 8 bf16
typedef __attribute__((ext_vector_type(4))) float    f32x4;   // MFMA accumulator
typedef __attribute__((ext_vector_type(4))) unsigned u32x4;

__device__ __forceinline__ unsigned short f2bf(float f) {
    unsigned int u = __float_as_uint(f);
    unsigned int r = u + 0x7fffu + ((u >> 16) & 1u);   // RNE
    return (unsigned short)(r >> 16);
}

// ---------------- K0: W2 f32 -> bf16 (row-major [h][k]) ----------------
__global__ void k0_w2(const float* __restrict__ W2w, unsigned short* __restrict__ w2bf) {
    int i = blockIdx.x * 256 + threadIdx.x;   // grid covers exactly 128*128
    w2bf[i] = f2bf(W2w[i]);
}

// ---------------- K1: a_g = v_n @ W1^T + (W1_b + W2_b); zero s_g -------
__global__ __launch_bounds__(128) void k1_ag(
    const float* __restrict__ node_emb,
    const int*   __restrict__ last_idx,
    const float* __restrict__ W1w,
    const float* __restrict__ W1b,
    const float* __restrict__ W2b,
    float* __restrict__ a_g,
    float* __restrict__ s_g)
{
    __shared__ float vn[4][H_DIM];
    const int tid = threadIdx.x;
    const int g0  = blockIdx.x * 4;
    #pragma unroll
    for (int g = 0; g < 4; g++) {
        int li = last_idx[g0 + g];
        vn[g][tid] = node_emb[(size_t)li * H_DIM + tid];
        s_g[(size_t)(g0 + g) * H_DIM + tid] = 0.f;   // zero-init for k2 atomics
    }
    __syncthreads();
    float b = W1b[tid] + W2b[tid];
    float a0 = b, a1 = b, a2 = b, a3 = b;
    const float* wrow = W1w + (size_t)tid * H_DIM;
    #pragma unroll 8
    for (int k = 0; k < H_DIM; k += 4) {
        float4 w = *reinterpret_cast<const float4*>(wrow + k);
        a0 += w.x * vn[0][k] + w.y * vn[0][k+1] + w.z * vn[0][k+2] + w.w * vn[0][k+3];
        a1 += w.x * vn[1][k] + w.y * vn[1][k+1] + w.z * vn[1][k+2] + w.w * vn[1][k+3];
        a2 += w.x * vn[2][k] + w.y * vn[2][k+1] + w.z * vn[2][k+2] + w.w * vn[2][k+3];
        a3 += w.x * vn[3][k] + w.y * vn[3][k+1] + w.z * vn[3][k+2] + w.w * vn[3][k+3];
    }
    a_g[(size_t)(g0 + 0) * H_DIM + tid] = a0;
    a_g[(size_t)(g0 + 1) * H_DIM + tid] = a1;
    a_g[(size_t)(g0 + 2) * H_DIM + tid] = a2;
    a_g[(size_t)(g0 + 3) * H_DIM + tid] = a3;
}

// ---------------- K2: fully fused alpha + segment-sum ------------------
// 6400 blocks x 256 threads. One barrier (W2 stage). Each WAVE owns 16
// nodes independently: swapped z-MFMA (z^T), in-lane alpha, identity-MFMA
// transpose for the segmented sum, global atomics per run.
__global__ __launch_bounds__(256, 4) void k2_fused(
    const float* __restrict__ node_emb,
    const float* __restrict__ num_count,
    const int*   __restrict__ seg_ids,
    const float* __restrict__ a_g,
    const unsigned short* __restrict__ w2bf,
    const float* __restrict__ q_w,
    const float* __restrict__ q_b,
    float* __restrict__ s_g)
{
    __shared__ __align__(16) char w2s[H_DIM * 256];   // 32 KB, swizzled

    const int tid = threadIdx.x;
    // --- stage W2 bf16 -> LDS (once per block), XOR swizzled ---
    {
        const uint4* wsrc = reinterpret_cast<const uint4*>(w2bf);
        #pragma unroll
        for (int i = 0; i < 8; i++) {
            int c = i * 256 + tid;
            uint4 v = wsrc[c];
            int byte = c << 4;
            int row  = byte >> 8;
            *reinterpret_cast<uint4*>(w2s + (byte ^ ((row & 7) << 4))) = v;
        }
    }

    const int lane = tid & 63;
    const int wid  = tid >> 6;
    const int l16 = lane & 15, lq = lane >> 4;
    const int nb  = (blockIdx.x * 4 + wid) * 16;      // this wave's 16 nodes

    // --- per-row scalars (row = l16) ---
    const int   sgl = seg_ids[nb + l16];
    const float ncl = num_count[nb + l16];
    const float qb0 = q_b[0];

    // --- A/B node fragments: row l16, cols lq*8 + ks*32 .. +7 (bf16) ---
    s16x8 af[4];
    const float* nrow = node_emb + (size_t)(nb + l16) * H_DIM + lq * 8;
    #pragma unroll
    for (int ks = 0; ks < 4; ks++) {
        float4 f0 = *reinterpret_cast<const float4*>(nrow + ks * 32);
        float4 f1 = *reinterpret_cast<const float4*>(nrow + ks * 32 + 4);
        unsigned p0, p1, p2, p3;
        asm("v_cvt_pk_bf16_f32 %0, %1, %2" : "=v"(p0) : "v"(f0.x), "v"(f0.y));
        asm("v_cvt_pk_bf16_f32 %0, %1, %2" : "=v"(p1) : "v"(f0.z), "v"(f0.w));
        asm("v_cvt_pk_bf16_f32 %0, %1, %2" : "=v"(p2) : "v"(f1.x), "v"(f1.y));
        asm("v_cvt_pk_bf16_f32 %0, %1, %2" : "=v"(p3) : "v"(f1.z), "v"(f1.w));
        union { u32x4 u; s16x8 s; } cv;
        cv.u = u32x4{p0, p1, p2, p3};
        af[ks] = cv.s;
    }

    __syncthreads();   // w2s ready (only barrier)

    // --- swapped MFMA: acc[nt] = z^T tile -> lane holds z[l16][h] -------
    // A = W2 frag (rows nt*16+l16), B = node frag (col j = node row l16)
    f32x4 acc[8];
    #pragma unroll
    for (int nt = 0; nt < 8; nt++) acc[nt] = f32x4{0.f, 0.f, 0.f, 0.f};
    #pragma unroll
    for (int ks = 0; ks < 4; ks++) {
        #pragma unroll
        for (int nt = 0; nt < 8; nt++) {
            int row  = nt * 16 + l16;
            int byte = (row << 8) | ((lq * 8 + ks * 32) << 1);
            byte ^= (row & 7) << 4;
            s16x8 wfr = *reinterpret_cast<const s16x8*>(w2s + byte);
            acc[nt] = __builtin_amdgcn_mfma_f32_16x16x32_bf16(wfr, af[ks], acc[nt], 0, 0, 0);
        }
    }
    // keep qv/ag loads below the MFMA block (VGPR pressure control)
    __builtin_amdgcn_sched_barrier(0);

    // --- alpha[l16] = sum_h sigmoid(z + a_g) * q_w[h]; h in-lane + xor16/32
    const float* agrow = a_g + (size_t)sgl * H_DIM + lq * 4;
    float p = 0.f;
    #pragma unroll
    for (int nt = 0; nt < 8; nt++) {
        float4 q4 = *reinterpret_cast<const float4*>(q_w + nt * 16 + lq * 4);
        float4 a4 = *reinterpret_cast<const float4*>(agrow + nt * 16);
        float zq[4] = {a4.x, a4.y, a4.z, a4.w};
        float qq[4] = {q4.x, q4.y, q4.z, q4.w};
        #pragma unroll
        for (int rr = 0; rr < 4; rr++) {
            float z = acc[nt][rr] + zq[rr];
            float e = __expf(-z);
            p += qq[rr] * __builtin_amdgcn_rcpf(1.f + e);
        }
    }
    p += __shfl_xor(p, 16, 64);
    p += __shfl_xor(p, 32, 64);
    const float coefl = ncl * (p + qb0);   // coef for row l16, at every lane

    // --- identity-MFMA transpose: accT[ks][b][rr] = node[lq*4+rr][ks*32+b*16+l16]
    s16x8 ib[2];
    #pragma unroll
    for (int b = 0; b < 2; b++) {
        int kk = l16 + 16 * b;
        #pragma unroll
        for (int e = 0; e < 8; e++)
            ib[b][e] = (kk == lq * 8 + e) ? (short)0x3F80 : (short)0;
    }
    f32x4 accT[4][2];
    #pragma unroll
    for (int ks = 0; ks < 4; ks++)
        #pragma unroll
        for (int b = 0; b < 2; b++)
            accT[ks][b] = __builtin_amdgcn_mfma_f32_16x16x32_bf16(
                              af[ks], ib[b], f32x4{0.f, 0.f, 0.f, 0.f}, 0, 0, 0);

    // --- segmented sum over the wave's 16 rows, run by run ---------------
    int r0 = 0;
    while (r0 < 16) {
        const int cur = __shfl(sgl, r0, 64);                 // wave-uniform
        unsigned long long diff = __ballot(sgl != cur) & 0xFFFFull;
        diff &= ~((1ull << r0) - 1ull);
        const int r1 = diff ? (int)__builtin_ctzll(diff) : 16;

        const float cmask = (sgl == cur) ? coefl : 0.f;      // masked coef of row l16
        float cm[4];
        #pragma unroll
        for (int rr = 0; rr < 4; rr++)
            cm[rr] = __shfl(cmask, lq * 4 + rr, 64);

        #pragma unroll
        for (int ks = 0; ks < 4; ks++) {
            #pragma unroll
            for (int b = 0; b < 2; b++) {
                float s = cm[0] * accT[ks][b][0] + cm[1] * accT[ks][b][1]
                        + cm[2] * accT[ks][b][2] + cm[3] * accT[ks][b][3];
                s += __shfl_xor(s, 16, 64);
                s += __shfl_xor(s, 32, 64);
                if (lq == 0)
                    atomicAdd(s_g + (size_t)cur * H_DIM + ks * 32 + b * 16 + l16, s);
            }
        }
        r0 = r1;
    }
}

// ---------------- K3: s_h = [v_n | s_g] @ W3^T + W3_b ------------------
__global__ __launch_bounds__(128) void k3_out(
    const float* __restrict__ node_emb,
    const int*   __restrict__ last_idx,
    const float* __restrict__ s_g,
    const float* __restrict__ W3w,
    const float* __restrict__ W3b,
    float* __restrict__ out)
{
    __shared__ float cat[8][2 * H_DIM];
    const int tid = threadIdx.x;
    const int g0  = blockIdx.x * 8;
    #pragma unroll
    for (int g = 0; g < 8; g++) {
        cat[g][tid]         = node_emb[(size_t)last_idx[g0 + g] * H_DIM + tid];
        cat[g][H_DIM + tid] = s_g[(size_t)(g0 + g) * H_DIM + tid];
    }
    __syncthreads();
    float acc[8];
    float b = W3b[tid];
    #pragma unroll
    for (int g = 0; g < 8; g++) acc[g] = b;
    const float* wrow = W3w + (size_t)tid * (2 * H_DIM);
    for (int k = 0; k < 2 * H_DIM; k += 4) {
        float4 w = *reinterpret_cast<const float4*>(wrow + k);
        #pragma unroll
        for (int g = 0; g < 8; g++)
            acc[g] += w.x * cat[g][k] + w.y * cat[g][k+1]
                    + w.z * cat[g][k+2] + w.w * cat[g][k+3];
    }
    #pragma unroll
    for (int g = 0; g < 8; g++)
        out[(size_t)(g0 + g) * H_DIM + tid] = acc[g];
}

extern "C" void kernel_launch(void* const* d_in, const int* in_sizes, int n_in,
                              void* d_out, int out_size, void* d_ws, size_t ws_size,
                              hipStream_t stream) {
    const float* node_emb  = (const float*)d_in[0];
    const float* num_count = (const float*)d_in[1];
    // d_in[2] sections: unused
    const int*   seg_ids   = (const int*)d_in[3];
    const int*   last_idx  = (const int*)d_in[4];
    // d_in[5..8] unused
    const float* W1w = (const float*)d_in[9];
    const float* W1b = (const float*)d_in[10];
    const float* W2w = (const float*)d_in[11];
    const float* W2b = (const float*)d_in[12];
    const float* qw  = (const float*)d_in[13];
    const float* qb  = (const float*)d_in[14];
    const float* W3w = (const float*)d_in[15];
    const float* W3b = (const float*)d_in[16];
    float* out = (float*)d_out;

    char* ws = (char*)d_ws;
    float* a_g = (float*)(ws);                          // 4 MB
    float* s_g = (float*)(ws + (4u << 20));             // 4 MB
    unsigned short* w2bf = (unsigned short*)(ws + (8u << 20));   // 32 KB

    k0_w2   <<<64,          256, 0, stream>>>(W2w, w2bf);
    k1_ag   <<<NGRAPH / 4,  128, 0, stream>>>(node_emb, last_idx, W1w, W1b, W2b, a_g, s_g);
    k2_fused<<<NTOTAL / 64, 256, 0, stream>>>(node_emb, num_count, seg_ids, a_g,
                                              w2bf, qw, qb, s_g);
    k3_out  <<<NGRAPH / 8,  128, 0, stream>>>(node_emb, last_idx, s_g, W3w, W3b, out);
}